// Round 1
// baseline (7020.741 us; speedup 1.0000x reference)
//
#include <hip/hip_runtime.h>
#include <cstdint>

#define N_B 64
#define T_T 512
#define D_D 1024
#define H_H 1024
#define G4H 4096

typedef __attribute__((ext_vector_type(8))) short short8;
typedef __attribute__((ext_vector_type(4))) float f32x4;

__device__ inline uint16_t f2bf(float f) {
    union { float f; uint32_t u; } v; v.f = f;
    uint32_t u = v.u + 0x7FFFu + ((v.u >> 16) & 1u);   // RNE
    return (uint16_t)(u >> 16);
}
__device__ inline float bf2f(uint16_t h) {
    union { uint32_t u; float f; } v; v.u = ((uint32_t)h) << 16;
    return v.f;
}
__device__ inline f32x4 mfma16(short8 a, short8 b, f32x4 c) {
    return __builtin_amdgcn_mfma_f32_16x16x32_bf16(a, b, c, 0, 0, 0);
}
__device__ inline float sigm(float x) {
    return 1.0f / (1.0f + __builtin_amdgcn_exp2f(-1.44269504f * x));
}
__device__ inline float tanh_f(float x) {
    float e = __builtin_amdgcn_exp2f(2.88539008f * x);  // e^(2x)
    return 1.0f - 2.0f / (e + 1.0f);
}
__device__ inline short8 cvt_pack(float4 u0, float4 u1) {
    short8 a;
    a[0] = (short)f2bf(u0.x); a[1] = (short)f2bf(u0.y);
    a[2] = (short)f2bf(u0.z); a[3] = (short)f2bf(u0.w);
    a[4] = (short)f2bf(u1.x); a[5] = (short)f2bf(u1.y);
    a[6] = (short)f2bf(u1.z); a[7] = (short)f2bf(u1.w);
    return a;
}

// ---- W (1024 x 4096 fp32) -> WT (4096 x 1024 bf16) ----
__global__ __launch_bounds__(256) void transposeW(const float* __restrict__ W,
                                                  uint16_t* __restrict__ WT) {
    __shared__ float tile[32][33];
    const int tx = threadIdx.x & 31, ty = threadIdx.x >> 5;
    const int n0 = blockIdx.x * 32, k0 = blockIdx.y * 32;
#pragma unroll
    for (int yy = 0; yy < 32; yy += 8)
        tile[ty + yy][tx] = W[(size_t)(k0 + ty + yy) * G4H + n0 + tx];
    __syncthreads();
#pragma unroll
    for (int yy = 0; yy < 32; yy += 8)
        WT[(size_t)(n0 + ty + yy) * 1024 + k0 + tx] = f2bf(tile[tx][ty + yy]);
}

// ---- h0 fp32 -> bf16 buffer0, zero c ----
__global__ void prep_h0(const float* __restrict__ h0, uint16_t* __restrict__ hb,
                        float* __restrict__ c) {
    int i = blockIdx.x * 256 + threadIdx.x;   // 65536 total
    hb[i] = f2bf(h0[i]);
    c[i] = 0.0f;
}

// ---- big GEMM: xW[t*64+nb][col] = x[nb][t][:] . Wx[:, col] ----
template<bool F32OUT>
__global__ __launch_bounds__(256) void xw_gemm(const float* __restrict__ x,
                                               const uint16_t* __restrict__ WxT,
                                               void* __restrict__ xWout) {
    const int tid = threadIdx.x;
    const int wv = tid >> 6, lane = tid & 63;
    const int quad = lane >> 4, r = lane & 15;
    const int t = blockIdx.y;
    const int n0 = blockIdx.x * 128 + wv * 32;

    f32x4 acc[4][2] = {};
    const float* xr[4];
#pragma unroll
    for (int mt = 0; mt < 4; mt++)
        xr[mt] = x + ((size_t)(mt * 16 + r) * T_T + t) * D_D;
    const uint16_t* b0p = WxT + (size_t)(n0 + r) * D_D;
    const uint16_t* b1p = WxT + (size_t)(n0 + 16 + r) * D_D;

#pragma unroll 4
    for (int k0 = 0; k0 < D_D; k0 += 32) {
        const int k = k0 + quad * 8;
        short8 b0 = *(const short8*)(b0p + k);
        short8 b1 = *(const short8*)(b1p + k);
#pragma unroll
        for (int mt = 0; mt < 4; mt++) {
            float4 u0 = *(const float4*)(xr[mt] + k);
            float4 u1 = *(const float4*)(xr[mt] + k + 4);
            short8 a = cvt_pack(u0, u1);
            acc[mt][0] = mfma16(a, b0, acc[mt][0]);
            acc[mt][1] = mfma16(a, b1, acc[mt][1]);
        }
    }
#pragma unroll
    for (int mt = 0; mt < 4; mt++)
#pragma unroll
        for (int nt = 0; nt < 2; nt++)
#pragma unroll
            for (int i = 0; i < 4; i++) {
                size_t row = (size_t)t * 64 + mt * 16 + quad * 4 + i;
                size_t idx = row * G4H + n0 + nt * 16 + r;
                if (F32OUT) ((float*)xWout)[idx] = acc[mt][nt][i];
                else        ((uint16_t*)xWout)[idx] = f2bf(acc[mt][nt][i]);
            }
}

// ---- one recurrence step ----
// MODE: 0 = fused (x@Wx inside, K=2048), 1 = precomputed xW bf16, 2 = xW fp32
// grid 256 blocks x 256 thr: bm = M-half (32 rows), bj = 8 h-cols; 4 waves split K.
template<int MODE>
__global__ __launch_bounds__(256) void lstm_step(
    const uint16_t* __restrict__ hin, uint16_t* __restrict__ hout,
    float* __restrict__ cst,
    const uint16_t* __restrict__ WhT, const uint16_t* __restrict__ WxT,
    const float* __restrict__ x, const void* __restrict__ xW,
    const float* __restrict__ bias, float* __restrict__ out, int t) {
    __shared__ float red[4][32 * 32];
    const int tid = threadIdx.x;
    const int wv = tid >> 6, lane = tid & 63;
    const int quad = lane >> 4, r = lane & 15;
    const int bm = blockIdx.x & 1, bj = blockIdx.x >> 1;
    const int j0 = bj * 8, m0 = bm * 32;

    // block's 32 gate-cols: idx = g*8+jj <-> col = g*1024 + j0 + jj
    const int colA = (r >> 3) * H_H + j0 + (r & 7);        // N-tile 0: gates 0,1
    const int colB = (2 + (r >> 3)) * H_H + j0 + (r & 7);  // N-tile 1: gates 2,3

    f32x4 acc[2][2] = {};

    if (MODE == 0) {
        if (wv < 2) {  // x part, K-half of 1024
            const int kb = wv * 512;
            const float* a0p = x + ((size_t)(m0 + r) * T_T + t) * D_D + kb;
            const float* a1p = x + ((size_t)(m0 + 16 + r) * T_T + t) * D_D + kb;
            const uint16_t* b0p = WxT + (size_t)colA * D_D + kb;
            const uint16_t* b1p = WxT + (size_t)colB * D_D + kb;
#pragma unroll 4
            for (int kk = 0; kk < 512; kk += 32) {
                const int k = kk + quad * 8;
                short8 b0 = *(const short8*)(b0p + k);
                short8 b1 = *(const short8*)(b1p + k);
                short8 a0 = cvt_pack(*(const float4*)(a0p + k), *(const float4*)(a0p + k + 4));
                short8 a1 = cvt_pack(*(const float4*)(a1p + k), *(const float4*)(a1p + k + 4));
                acc[0][0] = mfma16(a0, b0, acc[0][0]);
                acc[0][1] = mfma16(a0, b1, acc[0][1]);
                acc[1][0] = mfma16(a1, b0, acc[1][0]);
                acc[1][1] = mfma16(a1, b1, acc[1][1]);
            }
        } else {       // h part, K-half of 1024
            const int kb = (wv - 2) * 512;
            const uint16_t* a0p = hin + (size_t)(m0 + r) * H_H + kb;
            const uint16_t* a1p = hin + (size_t)(m0 + 16 + r) * H_H + kb;
            const uint16_t* b0p = WhT + (size_t)colA * H_H + kb;
            const uint16_t* b1p = WhT + (size_t)colB * H_H + kb;
#pragma unroll 4
            for (int kk = 0; kk < 512; kk += 32) {
                const int k = kk + quad * 8;
                short8 a0 = *(const short8*)(a0p + k);
                short8 a1 = *(const short8*)(a1p + k);
                short8 b0 = *(const short8*)(b0p + k);
                short8 b1 = *(const short8*)(b1p + k);
                acc[0][0] = mfma16(a0, b0, acc[0][0]);
                acc[0][1] = mfma16(a0, b1, acc[0][1]);
                acc[1][0] = mfma16(a1, b0, acc[1][0]);
                acc[1][1] = mfma16(a1, b1, acc[1][1]);
            }
        }
    } else {           // precomputed xW: only h@Wh, K=1024 split 4 ways
        const int kb = wv * 256;
        const uint16_t* a0p = hin + (size_t)(m0 + r) * H_H + kb;
        const uint16_t* a1p = hin + (size_t)(m0 + 16 + r) * H_H + kb;
        const uint16_t* b0p = WhT + (size_t)colA * H_H + kb;
        const uint16_t* b1p = WhT + (size_t)colB * H_H + kb;
#pragma unroll
        for (int kk = 0; kk < 256; kk += 32) {
            const int k = kk + quad * 8;
            short8 a0 = *(const short8*)(a0p + k);
            short8 a1 = *(const short8*)(a1p + k);
            short8 b0 = *(const short8*)(b0p + k);
            short8 b1 = *(const short8*)(b1p + k);
            acc[0][0] = mfma16(a0, b0, acc[0][0]);
            acc[0][1] = mfma16(a0, b1, acc[0][1]);
            acc[1][0] = mfma16(a1, b0, acc[1][0]);
            acc[1][1] = mfma16(a1, b1, acc[1][1]);
        }
    }

    // partial tiles -> LDS (C layout: row = quad*4+i, col = r)
#pragma unroll
    for (int mt = 0; mt < 2; mt++)
#pragma unroll
        for (int nt = 0; nt < 2; nt++)
#pragma unroll
            for (int i = 0; i < 4; i++) {
                int row = mt * 16 + quad * 4 + i;
                int ci = nt * 16 + r;
                red[wv][row * 32 + ci] = acc[mt][nt][i];
            }
    __syncthreads();

    // epilogue: one (batch-row, h-col) pair per thread
    const int mrow = tid >> 3, jj = tid & 7;
    const int m = m0 + mrow, j = j0 + jj;
    float av[4];
#pragma unroll
    for (int g = 0; g < 4; g++) {
        int idx = mrow * 32 + g * 8 + jj;
        float s = red[0][idx] + red[1][idx] + red[2][idx] + red[3][idx];
        if (MODE == 1) s += bf2f(((const uint16_t*)xW)[((size_t)t * 64 + m) * G4H + g * H_H + j]);
        if (MODE == 2) s += ((const float*)xW)[((size_t)t * 64 + m) * G4H + g * H_H + j];
        s += bias[g * H_H + j];
        av[g] = s;
    }
    float i_ = sigm(av[0]);
    float f_ = sigm(av[1]);
    float o_ = sigm(av[2]);
    float g_ = tanh_f(av[3]);
    float cp = cst[m * H_H + j];
    float cn = f_ * cp + i_ * g_;
    cst[m * H_H + j] = cn;
    float hn = o_ * tanh_f(cn);
    hout[m * H_H + j] = f2bf(hn);
    out[((size_t)m * T_T + t) * H_H + j] = hn;
}

extern "C" void kernel_launch(void* const* d_in, const int* in_sizes, int n_in,
                              void* d_out, int out_size, void* d_ws, size_t ws_size,
                              hipStream_t stream) {
    const float* x    = (const float*)d_in[0];
    const float* h0   = (const float*)d_in[1];
    const float* Wx   = (const float*)d_in[2];
    const float* Wh   = (const float*)d_in[3];
    const float* bias = (const float*)d_in[4];
    float* out = (float*)d_out;

    char* wsb = (char*)d_ws;
    uint16_t* WxT = (uint16_t*)(wsb + 0);            // 8 MB
    uint16_t* WhT = (uint16_t*)(wsb + 8388608);      // 8 MB
    uint16_t* hb  = (uint16_t*)(wsb + 16777216);     // 2 x 64x1024 bf16 = 256 KB
    float* cst    = (float*)(wsb + 17039360);        // 64x1024 fp32 = 256 KB
    void* xW      = (void*)(wsb + 17301504);
    const size_t base = 17301504ull;
    const size_t xw_elems = (size_t)G4H * N_B * T_T; // 134,217,728

    int mode = 0;                                    // fused fallback
    if (ws_size >= base + xw_elems * 4) mode = 2;    // fp32 xW (~554 MB)
    else if (ws_size >= base + xw_elems * 2) mode = 1; // bf16 xW (~286 MB)

    transposeW<<<dim3(128, 32), dim3(256), 0, stream>>>(Wx, WxT);
    transposeW<<<dim3(128, 32), dim3(256), 0, stream>>>(Wh, WhT);
    prep_h0<<<dim3(256), dim3(256), 0, stream>>>(h0, hb, cst);

    if (mode == 2) xw_gemm<true ><<<dim3(32, 512), dim3(256), 0, stream>>>(x, WxT, xW);
    if (mode == 1) xw_gemm<false><<<dim3(32, 512), dim3(256), 0, stream>>>(x, WxT, xW);

    for (int t = 0; t < T_T; t++) {
        uint16_t* hin  = hb + (size_t)(t & 1) * (N_B * H_H);
        uint16_t* hout = hb + (size_t)((t + 1) & 1) * (N_B * H_H);
        if (mode == 2)
            lstm_step<2><<<dim3(256), dim3(256), 0, stream>>>(hin, hout, cst, WhT, WxT, x, xW, bias, out, t);
        else if (mode == 1)
            lstm_step<1><<<dim3(256), dim3(256), 0, stream>>>(hin, hout, cst, WhT, WxT, x, xW, bias, out, t);
        else
            lstm_step<0><<<dim3(256), dim3(256), 0, stream>>>(hin, hout, cst, WhT, WxT, x, xW, bias, out, t);
    }
}